// Round 1
// baseline (3007.828 us; speedup 1.0000x reference)
//
#include <hip/hip_runtime.h>
#include <cstdint>
#include <cstddef>

// Problem dims (fixed by reference)
#define B_    64
#define T_    4096
#define H_    128
#define C1_   64
#define NCLS_ 40

__device__ __forceinline__ float fast_sigmoid(float x){
  // 1/(1+2^(-x*log2e))
  return __builtin_amdgcn_rcpf(1.0f + __builtin_amdgcn_exp2f(-1.4426950408889634f * x));
}
__device__ __forceinline__ float fast_tanh(float x){
  // 1 - 2/(2^(2x*log2e)+1); saturates correctly at +/-inf
  return 1.0f - 2.0f * __builtin_amdgcn_rcpf(__builtin_amdgcn_exp2f(2.8853900817779268f * x) + 1.0f);
}

// quad_perm DPP cross-lane (stays on VALU pipe, not LDS)
template<int CTRL>
__device__ __forceinline__ float qperm(float x){
  return __int_as_float(__builtin_amdgcn_update_dpp(0, __float_as_int(x), CTRL, 0xF, 0xF, true));
}

// ---------------- kernel 1: 3x3 second-moment stats of x over B*T ----------------
// stats[0..2] = sum x_d ; stats[3..8] = sum {x0x0,x0x1,x0x2,x1x1,x1x2,x2x2}
__global__ __launch_bounds__(256) void stats_kernel(const float* __restrict__ x,
                                                    float* __restrict__ stats){
  int t = blockIdx.x * 256 + threadIdx.x;           // 65536 threads, 12 floats (4 rows) each
  const float4* xv = (const float4*)x + (size_t)t * 3;
  float4 a = xv[0], b = xv[1], c = xv[2];
  float x0[4] = {a.x, a.w, b.z, c.y};
  float x1[4] = {a.y, b.x, b.w, c.z};
  float x2[4] = {a.z, b.y, c.x, c.w};
  float s[9] = {0,0,0,0,0,0,0,0,0};
  #pragma unroll
  for (int r=0;r<4;++r){
    s[0]+=x0[r]; s[1]+=x1[r]; s[2]+=x2[r];
    s[3]+=x0[r]*x0[r]; s[4]+=x0[r]*x1[r]; s[5]+=x0[r]*x2[r];
    s[6]+=x1[r]*x1[r]; s[7]+=x1[r]*x2[r]; s[8]+=x2[r]*x2[r];
  }
  __shared__ float red[9][256];
  #pragma unroll
  for (int j=0;j<9;++j) red[j][threadIdx.x] = s[j];
  __syncthreads();
  if (threadIdx.x < 9){
    float sum = 0.f;
    for (int i=0;i<256;++i) sum += red[threadIdx.x][i];
    atomicAdd(&stats[threadIdx.x], sum);
  }
}

// Fold conv + BN(train stats) + gamma/beta into per-channel affine over x (3 inputs).
// y_c = relu(A0*x0 + A1*x1 + A2*x2 + Bc). conv_b cancels exactly in (y-mu).
__device__ __forceinline__ void chan_affine(int c, const float* __restrict__ conv_w,
    const float* __restrict__ bn_g, const float* __restrict__ bn_b,
    const float* __restrict__ stats,
    float& A0, float& A1, float& A2, float& Bc){
  const float Ninv = 1.0f / (float)(B_*T_);
  float m0=stats[0]*Ninv, m1=stats[1]*Ninv, m2=stats[2]*Ninv;
  float c00=stats[3]*Ninv-m0*m0, c01=stats[4]*Ninv-m0*m1, c02=stats[5]*Ninv-m0*m2;
  float c11=stats[6]*Ninv-m1*m1, c12=stats[7]*Ninv-m1*m2, c22=stats[8]*Ninv-m2*m2;
  float w0=conv_w[c*3+0], w1=conv_w[c*3+1], w2=conv_w[c*3+2];
  float var = w0*(w0*c00 + 2.f*(w1*c01 + w2*c02)) + w1*(w1*c11 + 2.f*w2*c12) + w2*w2*c22;
  float sc = bn_g[c] * rsqrtf(var + 1e-5f);
  A0 = w0*sc; A1 = w1*sc; A2 = w2*sc;
  Bc = bn_b[c] - (w0*m0 + w1*m1 + w2*m2)*sc;
}

// ---------------- kernel 2: x-gates GEMM ----------------
// xg[bt][j] = b_ih[j]+b_hh[j] + sum_c w_ih[j][c]*relu(affine_c(x[bt])) , j in [0,512)
__global__ __launch_bounds__(256,2) void xg_kernel(
    const float* __restrict__ x, const float* __restrict__ conv_w,
    const float* __restrict__ bn_g, const float* __restrict__ bn_b,
    const float* __restrict__ w_ih, const float* __restrict__ b_ih,
    const float* __restrict__ b_hh, const float* __restrict__ stats,
    float* __restrict__ xg){
  constexpr int ROWS = 128;
  __shared__ __align__(16) float yAff[C1_][4];
  __shared__ __align__(16) float ybuf[ROWS][C1_];   // 32 KB
  __shared__ __align__(16) float xrow[ROWS*3];
  int tid = threadIdx.x;
  if (tid < C1_){
    float A0,A1,A2,Bc; chan_affine(tid, conv_w, bn_g, bn_b, stats, A0,A1,A2,Bc);
    yAff[tid][0]=A0; yAff[tid][1]=A1; yAff[tid][2]=A2; yAff[tid][3]=Bc;
  }
  // per-thread w_ih rows (gates tid and tid+256) in registers: 128 VGPRs
  float wi0[64], wi1[64];
  {
    const float4* p0 = (const float4*)(w_ih + (size_t)tid*C1_);
    const float4* p1 = (const float4*)(w_ih + (size_t)(tid+256)*C1_);
    #pragma unroll
    for (int i=0;i<16;++i){
      float4 v = p0[i]; wi0[4*i]=v.x; wi0[4*i+1]=v.y; wi0[4*i+2]=v.z; wi0[4*i+3]=v.w;
      float4 u = p1[i]; wi1[4*i]=u.x; wi1[4*i+1]=u.y; wi1[4*i+2]=u.z; wi1[4*i+3]=u.w;
    }
  }
  float bias0 = b_ih[tid] + b_hh[tid];
  float bias1 = b_ih[tid+256] + b_hh[tid+256];
  size_t row0 = (size_t)blockIdx.x * ROWS;
  if (tid < 96) ((float4*)xrow)[tid] = ((const float4*)(x + row0*3))[tid];
  __syncthreads();
  #pragma unroll
  for (int i=0;i<32;++i){
    int v = tid + i*256; int r = v>>6, c = v&63;
    float yv = fmaf(yAff[c][0], xrow[r*3], fmaf(yAff[c][1], xrow[r*3+1],
               fmaf(yAff[c][2], xrow[r*3+2], yAff[c][3])));
    ybuf[r][c] = fmaxf(yv, 0.f);
  }
  __syncthreads();
  float* outp = xg + row0*512;
  for (int r=0;r<ROWS;++r){
    float a0 = bias0, a1 = bias1;
    #pragma unroll
    for (int c4=0;c4<C1_;c4+=4){
      float4 y4 = *(const float4*)&ybuf[r][c4];   // full-wave broadcast, conflict-free
      a0 = fmaf(wi0[c4],y4.x, fmaf(wi0[c4+1],y4.y, fmaf(wi0[c4+2],y4.z, fmaf(wi0[c4+3],y4.w, a0))));
      a1 = fmaf(wi1[c4],y4.x, fmaf(wi1[c4+1],y4.y, fmaf(wi1[c4+2],y4.z, fmaf(wi1[c4+3],y4.w, a1))));
    }
    outp[(size_t)r*512 + tid]       = a0;   // coalesced
    outp[(size_t)r*512 + tid + 256] = a1;
  }
}

// ---------------- kernel 3: persistent per-batch LSTM ----------------
// 64 blocks x 512 threads. thread t: k = t>>2 (h index), q = t&3 (32-wide k-window).
// Each thread computes partial gates {i,f,g,o}[k] over its window, quad-reduces via DPP,
// owns c[k] in a register; h double-buffered in padded LDS (disjoint banks per q).
// FUSED variant recomputes the conv/BN/ReLU input on the fly (no workspace GEMM).
template<bool FUSED>
__global__ __launch_bounds__(512,2) void lstm_kernel(
    const float* __restrict__ xg, const float* __restrict__ x,
    const float* __restrict__ conv_w, const float* __restrict__ bn_g,
    const float* __restrict__ bn_b, const float* __restrict__ stats,
    const float* __restrict__ w_ih, const float* __restrict__ b_ih,
    const float* __restrict__ b_hh, const float* __restrict__ w_hh,
    const float* __restrict__ h0, const float* __restrict__ c0,
    const float* __restrict__ out_w, const float* __restrict__ out_b,
    float* __restrict__ out){
  int b = blockIdx.x, t = threadIdx.x;
  int k = t >> 2, q = t & 3;
  __shared__ __align__(16) float hbuf[2][144];   // 128 + 4-float pad per 32 → q-windows on disjoint banks
  __shared__ __align__(16) float ybuf[2][C1_];   // FUSED only
  // recurrent weights: w_hh rows {k,128+k,256+k,384+k}, cols [q*32, q*32+32) → 128 VGPRs
  float w[4][32];
  #pragma unroll
  for (int g=0; g<4; ++g){
    const float4* p = (const float4*)(w_hh + (size_t)(g*H_ + k)*H_ + q*32);
    #pragma unroll
    for (int i=0;i<8;++i){
      float4 v = p[i];
      w[g][4*i]=v.x; w[g][4*i+1]=v.y; w[g][4*i+2]=v.z; w[g][4*i+3]=v.w;
    }
  }
  float wiF[4][16]; float biasF[4] = {0,0,0,0};
  float ya0=0, ya1=0, ya2=0, ya3=0;
  float xcur0=0, xcur1=0, xcur2=0;
  const float* xb = x + (size_t)b*T_*3;
  if constexpr (FUSED){
    #pragma unroll
    for (int g=0; g<4; ++g){
      const float4* p = (const float4*)(w_ih + (size_t)(g*H_ + k)*C1_ + q*16);
      #pragma unroll
      for (int i=0;i<4;++i){
        float4 v = p[i];
        wiF[g][4*i]=v.x; wiF[g][4*i+1]=v.y; wiF[g][4*i+2]=v.z; wiF[g][4*i+3]=v.w;
      }
      biasF[g] = b_ih[g*H_+k] + b_hh[g*H_+k];
    }
    if (t < C1_){
      chan_affine(t, conv_w, bn_g, bn_b, stats, ya0, ya1, ya2, ya3);
      float y0 = fmaf(ya0, xb[0], fmaf(ya1, xb[1], fmaf(ya2, xb[2], ya3)));
      ybuf[0][t] = fmaxf(y0, 0.f);
      xcur0 = xb[3]; xcur1 = xb[4]; xcur2 = xb[5];   // x[t=1] prefetch
    }
  }
  float c = c0[(size_t)b*H_ + k];
  if (q == 0) hbuf[0][k + (k>>5)*4] = h0[(size_t)b*H_ + k];
  const float* xgb = xg + (size_t)b*T_*512;
  float xin0=0, xin1=0, xin2=0, xin3=0;
  if constexpr (!FUSED){
    xin0 = xgb[0*H_+k]; xin1 = xgb[1*H_+k]; xin2 = xgb[2*H_+k]; xin3 = xgb[3*H_+k];
  }
  __syncthreads();

  for (int step=0; step<T_; ++step){
    int p = step & 1;
    int tn = (step+1 < T_) ? step+1 : step;
    float xn0=0, xn1=0, xn2=0, xn3=0;
    if constexpr (!FUSED){                        // prefetch next-step x-gates (latency hidden)
      const float* xgt = xgb + (size_t)tn*512;
      xn0 = xgt[0*H_+k]; xn1 = xgt[1*H_+k]; xn2 = xgt[2*H_+k]; xn3 = xgt[3*H_+k];
    }
    float acc[4] = {0.f,0.f,0.f,0.f};
    const float* hb = &hbuf[p][q*36];             // 144B stride → disjoint banks per q
    #pragma unroll
    for (int i=0;i<8;++i){
      float4 hv = *(const float4*)(hb + 4*i);
      #pragma unroll
      for (int g=0; g<4; ++g){
        acc[g] = fmaf(w[g][4*i+0], hv.x, acc[g]);
        acc[g] = fmaf(w[g][4*i+1], hv.y, acc[g]);
        acc[g] = fmaf(w[g][4*i+2], hv.z, acc[g]);
        acc[g] = fmaf(w[g][4*i+3], hv.w, acc[g]);
      }
    }
    if constexpr (FUSED){                         // x-part over c-window [q*16, q*16+16)
      const float* yb = &ybuf[p][q*16];
      #pragma unroll
      for (int i=0;i<4;++i){
        float4 yv = *(const float4*)(yb + 4*i);
        #pragma unroll
        for (int g=0; g<4; ++g){
          acc[g] = fmaf(wiF[g][4*i+0], yv.x, acc[g]);
          acc[g] = fmaf(wiF[g][4*i+1], yv.y, acc[g]);
          acc[g] = fmaf(wiF[g][4*i+2], yv.z, acc[g]);
          acc[g] = fmaf(wiF[g][4*i+3], yv.w, acc[g]);
        }
      }
    }
    #pragma unroll
    for (int g=0; g<4; ++g){                      // quad butterfly on VALU (DPP)
      acc[g] += qperm<0xB1>(acc[g]);              // quad_perm [1,0,3,2]
      acc[g] += qperm<0x4E>(acc[g]);              // quad_perm [2,3,0,1]
    }
    float gi, gf, gg, go;
    if constexpr (!FUSED){ gi = acc[0]+xin0; gf = acc[1]+xin1; gg = acc[2]+xin2; go = acc[3]+xin3; }
    else                 { gi = acc[0]+biasF[0]; gf = acc[1]+biasF[1]; gg = acc[2]+biasF[2]; go = acc[3]+biasF[3]; }
    float I = fast_sigmoid(gi), F = fast_sigmoid(gf);
    float G = fast_tanh(gg),    O = fast_sigmoid(go);
    c = fmaf(F, c, I*G);
    float h = O * fast_tanh(c);
    if (q == 0) hbuf[1-p][k + (k>>5)*4] = h;
    if constexpr (!FUSED){ xin0=xn0; xin1=xn1; xin2=xn2; xin3=xn3; }
    else {
      if (t < C1_){                               // produce y[step+1] for next iter
        float yn = fmaf(ya0, xcur0, fmaf(ya1, xcur1, fmaf(ya2, xcur2, ya3)));
        ybuf[1-p][t] = fmaxf(yn, 0.f);
        int t2 = (step+2 < T_) ? step+2 : T_-1;
        xcur0 = xb[(size_t)t2*3]; xcur1 = xb[(size_t)t2*3+1]; xcur2 = xb[(size_t)t2*3+2];
      }
    }
    __syncthreads();
  }
  // classifier epilogue on final h (in hbuf[0]; last step p=1 wrote buffer 0)
  if (t < NCLS_){
    float s = out_b[t];
    #pragma unroll 8
    for (int kk=0; kk<H_; ++kk)
      s = fmaf(out_w[t*H_ + kk], hbuf[0][kk + (kk>>5)*4], s);
    out[(size_t)b*NCLS_ + t] = s;
  }
}

extern "C" void kernel_launch(void* const* d_in, const int* in_sizes, int n_in,
                              void* d_out, int out_size, void* d_ws, size_t ws_size,
                              hipStream_t stream){
  const float* x      = (const float*)d_in[0];
  const float* conv_w = (const float*)d_in[1];
  // d_in[2] = conv_b: cancels exactly inside BN(train-stats) — unused
  const float* bn_g   = (const float*)d_in[3];
  const float* bn_b   = (const float*)d_in[4];
  const float* w_ih   = (const float*)d_in[5];
  const float* b_ih   = (const float*)d_in[6];
  const float* w_hh   = (const float*)d_in[7];
  const float* b_hh   = (const float*)d_in[8];
  const float* out_w  = (const float*)d_in[9];
  const float* out_b  = (const float*)d_in[10];
  const float* h0     = (const float*)d_in[11];
  const float* c0     = (const float*)d_in[12];
  float* out   = (float*)d_out;
  float* stats = (float*)d_ws;
  float* xg    = (float*)((char*)d_ws + 4096);
  const size_t need = 4096 + (size_t)B_*T_*512*sizeof(float);

  hipMemsetAsync(d_ws, 0, 64, stream);            // zero the 9 stat accumulators
  stats_kernel<<<256, 256, 0, stream>>>(x, stats);
  if (ws_size >= need){
    xg_kernel<<<(B_*T_)/128, 256, 0, stream>>>(x, conv_w, bn_g, bn_b, w_ih, b_ih, b_hh, stats, xg);
    lstm_kernel<false><<<B_, 512, 0, stream>>>(xg, x, conv_w, bn_g, bn_b, stats,
                                               w_ih, b_ih, b_hh, w_hh, h0, c0, out_w, out_b, out);
  } else {
    lstm_kernel<true><<<B_, 512, 0, stream>>>(xg, x, conv_w, bn_g, bn_b, stats,
                                              w_ih, b_ih, b_hh, w_hh, h0, c0, out_w, out_b, out);
  }
}

// Round 2
// 2682.748 us; speedup vs baseline: 1.1212x; 1.1212x over previous
//
#include <hip/hip_runtime.h>
#include <cstdint>
#include <cstddef>

// Problem dims (fixed by reference)
#define B_    64
#define T_    4096
#define H_    128
#define C1_   64
#define NCLS_ 40

typedef _Float16 half2_t __attribute__((ext_vector_type(2)));

__device__ __forceinline__ float fdot2(half2_t a, half2_t b, float c){
#if defined(__has_builtin) && __has_builtin(__builtin_amdgcn_fdot2)
  return __builtin_amdgcn_fdot2(a, b, c, false);   // v_dot2_f32_f16, full-rate
#else
  return fmaf((float)a.x, (float)b.x, fmaf((float)a.y, (float)b.y, c));
#endif
}
__device__ __forceinline__ half2_t bc2(unsigned int u){ return __builtin_bit_cast(half2_t, u); }
__device__ __forceinline__ half2_t pack2(float a, float b){
  half2_t r; r.x = (_Float16)a; r.y = (_Float16)b; return r;   // RTNE (unbiased)
}

__device__ __forceinline__ float fast_sigmoid(float x){
  return __builtin_amdgcn_rcpf(1.0f + __builtin_amdgcn_exp2f(-1.4426950408889634f * x));
}
__device__ __forceinline__ float fast_tanh(float x){
  return 1.0f - 2.0f * __builtin_amdgcn_rcpf(__builtin_amdgcn_exp2f(2.8853900817779268f * x) + 1.0f);
}

template<int CTRL>
__device__ __forceinline__ float qperm(float x){
  return __int_as_float(__builtin_amdgcn_update_dpp(0, __float_as_int(x), CTRL, 0xF, 0xF, true));
}

// ---------------- kernel 1: 3x3 second-moment stats of x over B*T ----------------
__global__ __launch_bounds__(256) void stats_kernel(const float* __restrict__ x,
                                                    float* __restrict__ stats){
  int t = blockIdx.x * 256 + threadIdx.x;
  const float4* xv = (const float4*)x + (size_t)t * 3;
  float4 a = xv[0], b = xv[1], c = xv[2];
  float x0[4] = {a.x, a.w, b.z, c.y};
  float x1[4] = {a.y, b.x, b.w, c.z};
  float x2[4] = {a.z, b.y, c.x, c.w};
  float s[9] = {0,0,0,0,0,0,0,0,0};
  #pragma unroll
  for (int r=0;r<4;++r){
    s[0]+=x0[r]; s[1]+=x1[r]; s[2]+=x2[r];
    s[3]+=x0[r]*x0[r]; s[4]+=x0[r]*x1[r]; s[5]+=x0[r]*x2[r];
    s[6]+=x1[r]*x1[r]; s[7]+=x1[r]*x2[r]; s[8]+=x2[r]*x2[r];
  }
  __shared__ float red[9][256];
  #pragma unroll
  for (int j=0;j<9;++j) red[j][threadIdx.x] = s[j];
  __syncthreads();
  if (threadIdx.x < 9){
    float sum = 0.f;
    for (int i=0;i<256;++i) sum += red[threadIdx.x][i];
    atomicAdd(&stats[threadIdx.x], sum);
  }
}

// Fold conv + BN(train stats) + gamma/beta into per-channel affine. conv_b cancels.
__device__ __forceinline__ void chan_affine(int c, const float* __restrict__ conv_w,
    const float* __restrict__ bn_g, const float* __restrict__ bn_b,
    const float* __restrict__ stats,
    float& A0, float& A1, float& A2, float& Bc){
  const float Ninv = 1.0f / (float)(B_*T_);
  float m0=stats[0]*Ninv, m1=stats[1]*Ninv, m2=stats[2]*Ninv;
  float c00=stats[3]*Ninv-m0*m0, c01=stats[4]*Ninv-m0*m1, c02=stats[5]*Ninv-m0*m2;
  float c11=stats[6]*Ninv-m1*m1, c12=stats[7]*Ninv-m1*m2, c22=stats[8]*Ninv-m2*m2;
  float w0=conv_w[c*3+0], w1=conv_w[c*3+1], w2=conv_w[c*3+2];
  float var = w0*(w0*c00 + 2.f*(w1*c01 + w2*c02)) + w1*(w1*c11 + 2.f*w2*c12) + w2*w2*c22;
  float sc = bn_g[c] * rsqrtf(var + 1e-5f);
  A0 = w0*sc; A1 = w1*sc; A2 = w2*sc;
  Bc = bn_b[c] - (w0*m0 + w1*m1 + w2*m2)*sc;
}

// ---------------- kernel 2: x-gates GEMM (f16 output) ----------------
__global__ __launch_bounds__(256,2) void xg_kernel(
    const float* __restrict__ x, const float* __restrict__ conv_w,
    const float* __restrict__ bn_g, const float* __restrict__ bn_b,
    const float* __restrict__ w_ih, const float* __restrict__ b_ih,
    const float* __restrict__ b_hh, const float* __restrict__ stats,
    _Float16* __restrict__ xg){
  constexpr int ROWS = 128;
  __shared__ __align__(16) float yAff[C1_][4];
  __shared__ __align__(16) float ybuf[ROWS][C1_];
  __shared__ __align__(16) float xrow[ROWS*3];
  int tid = threadIdx.x;
  if (tid < C1_){
    float A0,A1,A2,Bc; chan_affine(tid, conv_w, bn_g, bn_b, stats, A0,A1,A2,Bc);
    yAff[tid][0]=A0; yAff[tid][1]=A1; yAff[tid][2]=A2; yAff[tid][3]=Bc;
  }
  float wi0[64], wi1[64];
  {
    const float4* p0 = (const float4*)(w_ih + (size_t)tid*C1_);
    const float4* p1 = (const float4*)(w_ih + (size_t)(tid+256)*C1_);
    #pragma unroll
    for (int i=0;i<16;++i){
      float4 v = p0[i]; wi0[4*i]=v.x; wi0[4*i+1]=v.y; wi0[4*i+2]=v.z; wi0[4*i+3]=v.w;
      float4 u = p1[i]; wi1[4*i]=u.x; wi1[4*i+1]=u.y; wi1[4*i+2]=u.z; wi1[4*i+3]=u.w;
    }
  }
  float bias0 = b_ih[tid] + b_hh[tid];
  float bias1 = b_ih[tid+256] + b_hh[tid+256];
  size_t row0 = (size_t)blockIdx.x * ROWS;
  if (tid < 96) ((float4*)xrow)[tid] = ((const float4*)(x + row0*3))[tid];
  __syncthreads();
  #pragma unroll
  for (int i=0;i<32;++i){
    int v = tid + i*256; int r = v>>6, c = v&63;
    float yv = fmaf(yAff[c][0], xrow[r*3], fmaf(yAff[c][1], xrow[r*3+1],
               fmaf(yAff[c][2], xrow[r*3+2], yAff[c][3])));
    ybuf[r][c] = fmaxf(yv, 0.f);
  }
  __syncthreads();
  _Float16* outp = xg + row0*512;
  for (int r=0;r<ROWS;++r){
    float a0 = bias0, a1 = bias1;
    #pragma unroll
    for (int c4=0;c4<C1_;c4+=4){
      float4 y4 = *(const float4*)&ybuf[r][c4];
      a0 = fmaf(wi0[c4],y4.x, fmaf(wi0[c4+1],y4.y, fmaf(wi0[c4+2],y4.z, fmaf(wi0[c4+3],y4.w, a0))));
      a1 = fmaf(wi1[c4],y4.x, fmaf(wi1[c4+1],y4.y, fmaf(wi1[c4+2],y4.z, fmaf(wi1[c4+3],y4.w, a1))));
    }
    outp[(size_t)r*512 + tid]       = (_Float16)a0;
    outp[(size_t)r*512 + tid + 256] = (_Float16)a1;
  }
}

// ---------------- kernel 3: persistent per-batch LSTM, f16 dot2 datapath ----------------
// 64 blocks x 512 threads. thread t: k = t>>2, q = t&3 (32-wide h window, 16-wide y window).
// Weights live as half2 in VGPRs (96 regs); h/y cross LDS as f16; acc/c/activations fp32.
template<bool FUSED>
__global__ __launch_bounds__(512,2) void lstm_kernel(
    const _Float16* __restrict__ xg, const float* __restrict__ x,
    const float* __restrict__ conv_w, const float* __restrict__ bn_g,
    const float* __restrict__ bn_b, const float* __restrict__ stats,
    const float* __restrict__ w_ih, const float* __restrict__ b_ih,
    const float* __restrict__ b_hh, const float* __restrict__ w_hh,
    const float* __restrict__ h0, const float* __restrict__ c0,
    const float* __restrict__ out_w, const float* __restrict__ out_b,
    float* __restrict__ out){
  int b = blockIdx.x, t = threadIdx.x;
  int k = t >> 2, q = t & 3;
  __shared__ __align__(16) _Float16 hbuf[2][H_];    // 256 B/buffer; reads are quad-broadcast
  __shared__ __align__(16) _Float16 ybuf[2][C1_];   // FUSED only

  // recurrent weights as half2: rows {k,128+k,256+k,384+k}, cols [q*32, q*32+32)
  half2_t wh[4][16];
  #pragma unroll
  for (int g=0; g<4; ++g){
    const float4* p = (const float4*)(w_hh + (size_t)(g*H_ + k)*H_ + q*32);
    #pragma unroll
    for (int i=0;i<8;++i){
      float4 v = p[i];
      wh[g][2*i]   = pack2(v.x, v.y);
      wh[g][2*i+1] = pack2(v.z, v.w);
    }
  }
  half2_t wy[4][8]; float biasF[4] = {0,0,0,0};
  float ya0=0, ya1=0, ya2=0, ya3=0;
  float xcur0=0, xcur1=0, xcur2=0;
  const float* xb = x + (size_t)b*T_*3;
  if constexpr (FUSED){
    #pragma unroll
    for (int g=0; g<4; ++g){
      const float4* p = (const float4*)(w_ih + (size_t)(g*H_ + k)*C1_ + q*16);
      #pragma unroll
      for (int i=0;i<4;++i){
        float4 v = p[i];
        wy[g][2*i]   = pack2(v.x, v.y);
        wy[g][2*i+1] = pack2(v.z, v.w);
      }
      biasF[g] = b_ih[g*H_+k] + b_hh[g*H_+k];
    }
    if (t < C1_){
      chan_affine(t, conv_w, bn_g, bn_b, stats, ya0, ya1, ya2, ya3);
      float y0 = fmaf(ya0, xb[0], fmaf(ya1, xb[1], fmaf(ya2, xb[2], ya3)));
      ybuf[0][t] = (_Float16)fmaxf(y0, 0.f);
      xcur0 = xb[3]; xcur1 = xb[4]; xcur2 = xb[5];   // x[t=1] prefetch
    }
  }
  float c = c0[(size_t)b*H_ + k];
  if (q == 0) hbuf[0][k] = (_Float16)h0[(size_t)b*H_ + k];
  const _Float16* xgb = xg + (size_t)b*T_*512;
  float xin0=0, xin1=0, xin2=0, xin3=0;
  if constexpr (!FUSED){
    xin0 = (float)xgb[0*H_+k]; xin1 = (float)xgb[1*H_+k];
    xin2 = (float)xgb[2*H_+k]; xin3 = (float)xgb[3*H_+k];
  }
  __syncthreads();

  #pragma unroll 2
  for (int step=0; step<T_; ++step){
    int p = step & 1;                       // const-folded per unrolled copy
    float xn0=0, xn1=0, xn2=0, xn3=0;
    if constexpr (!FUSED){                  // prefetch next-step x-gates
      int tn = (step+1 < T_) ? step+1 : step;
      const _Float16* xgt = xgb + (size_t)tn*512;
      xn0 = (float)xgt[0*H_+k]; xn1 = (float)xgt[1*H_+k];
      xn2 = (float)xgt[2*H_+k]; xn3 = (float)xgt[3*H_+k];
    }
    float acc[4] = {0.f,0.f,0.f,0.f};
    const _Float16* hb = &hbuf[p][q*32];
    #pragma unroll
    for (int i=0;i<4;++i){
      uint4 hv = *(const uint4*)(hb + 8*i);
      half2_t h0_ = bc2(hv.x), h1_ = bc2(hv.y), h2_ = bc2(hv.z), h3_ = bc2(hv.w);
      #pragma unroll
      for (int g=0; g<4; ++g){
        acc[g] = fdot2(wh[g][4*i+0], h0_, acc[g]);
        acc[g] = fdot2(wh[g][4*i+1], h1_, acc[g]);
        acc[g] = fdot2(wh[g][4*i+2], h2_, acc[g]);
        acc[g] = fdot2(wh[g][4*i+3], h3_, acc[g]);
      }
    }
    if constexpr (FUSED){
      const _Float16* yb = &ybuf[p][q*16];
      #pragma unroll
      for (int i=0;i<2;++i){
        uint4 yv = *(const uint4*)(yb + 8*i);
        half2_t y0_ = bc2(yv.x), y1_ = bc2(yv.y), y2_ = bc2(yv.z), y3_ = bc2(yv.w);
        #pragma unroll
        for (int g=0; g<4; ++g){
          acc[g] = fdot2(wy[g][4*i+0], y0_, acc[g]);
          acc[g] = fdot2(wy[g][4*i+1], y1_, acc[g]);
          acc[g] = fdot2(wy[g][4*i+2], y2_, acc[g]);
          acc[g] = fdot2(wy[g][4*i+3], y3_, acc[g]);
        }
      }
    }
    #pragma unroll
    for (int g=0; g<4; ++g){                // quad butterfly on VALU (DPP)
      acc[g] += qperm<0xB1>(acc[g]);        // quad_perm [1,0,3,2]
      acc[g] += qperm<0x4E>(acc[g]);        // quad_perm [2,3,0,1]
    }
    float gi, gf, gg, go;
    if constexpr (!FUSED){ gi = acc[0]+xin0; gf = acc[1]+xin1; gg = acc[2]+xin2; go = acc[3]+xin3; }
    else                 { gi = acc[0]+biasF[0]; gf = acc[1]+biasF[1]; gg = acc[2]+biasF[2]; go = acc[3]+biasF[3]; }
    float I = fast_sigmoid(gi), F = fast_sigmoid(gf);
    float G = fast_tanh(gg),    O = fast_sigmoid(go);
    c = fmaf(F, c, I*G);
    float h = O * fast_tanh(c);
    if (q == 0) hbuf[1-p][k] = (_Float16)h;
    if constexpr (!FUSED){ xin0=xn0; xin1=xn1; xin2=xn2; xin3=xn3; }
    else {
      if (t < C1_){                         // wave 0 produces y[step+1]
        float yn = fmaf(ya0, xcur0, fmaf(ya1, xcur1, fmaf(ya2, xcur2, ya3)));
        ybuf[1-p][t] = (_Float16)fmaxf(yn, 0.f);
        int t2 = (step+2 < T_) ? step+2 : T_-1;
        xcur0 = xb[(size_t)t2*3]; xcur1 = xb[(size_t)t2*3+1]; xcur2 = xb[(size_t)t2*3+2];
      }
    }
    __syncthreads();
  }
  // classifier epilogue on final h (T even → buffer 0)
  if (t < NCLS_){
    float s = out_b[t];
    #pragma unroll 8
    for (int kk=0; kk<H_; ++kk)
      s = fmaf(out_w[t*H_ + kk], (float)hbuf[0][kk], s);
    out[(size_t)b*NCLS_ + t] = s;
  }
}

extern "C" void kernel_launch(void* const* d_in, const int* in_sizes, int n_in,
                              void* d_out, int out_size, void* d_ws, size_t ws_size,
                              hipStream_t stream){
  const float* x      = (const float*)d_in[0];
  const float* conv_w = (const float*)d_in[1];
  // d_in[2] = conv_b: cancels exactly inside BN(train stats) — unused
  const float* bn_g   = (const float*)d_in[3];
  const float* bn_b   = (const float*)d_in[4];
  const float* w_ih   = (const float*)d_in[5];
  const float* b_ih   = (const float*)d_in[6];
  const float* w_hh   = (const float*)d_in[7];
  const float* b_hh   = (const float*)d_in[8];
  const float* out_w  = (const float*)d_in[9];
  const float* out_b  = (const float*)d_in[10];
  const float* h0     = (const float*)d_in[11];
  const float* c0     = (const float*)d_in[12];
  float* out      = (float*)d_out;
  float* stats    = (float*)d_ws;
  _Float16* xg    = (_Float16*)((char*)d_ws + 4096);
  const size_t need = 4096 + (size_t)B_*T_*512*sizeof(_Float16);   // ~268 MB

  hipMemsetAsync(d_ws, 0, 64, stream);
  stats_kernel<<<256, 256, 0, stream>>>(x, stats);
  if (ws_size >= need){
    xg_kernel<<<(B_*T_)/128, 256, 0, stream>>>(x, conv_w, bn_g, bn_b, w_ih, b_ih, b_hh, stats, xg);
    lstm_kernel<false><<<B_, 512, 0, stream>>>(xg, x, conv_w, bn_g, bn_b, stats,
                                               w_ih, b_ih, b_hh, w_hh, h0, c0, out_w, out_b, out);
  } else {
    lstm_kernel<true><<<B_, 512, 0, stream>>>(xg, x, conv_w, bn_g, bn_b, stats,
                                              w_ih, b_ih, b_hh, w_hh, h0, c0, out_w, out_b, out);
  }
}

// Round 3
// 2610.638 us; speedup vs baseline: 1.1521x; 1.0276x over previous
//
#include <hip/hip_runtime.h>
#include <cstdint>
#include <cstddef>

// Problem dims (fixed by reference)
#define B_    64
#define T_    4096
#define H_    128
#define C1_   64
#define NCLS_ 40

typedef _Float16 half2_t __attribute__((ext_vector_type(2)));

__device__ __forceinline__ float fdot2(half2_t a, half2_t b, float c){
#if defined(__has_builtin) && __has_builtin(__builtin_amdgcn_fdot2)
  return __builtin_amdgcn_fdot2(a, b, c, false);   // v_dot2_f32_f16, full-rate
#else
  return fmaf((float)a.x, (float)b.x, fmaf((float)a.y, (float)b.y, c));
#endif
}
__device__ __forceinline__ half2_t bc2(unsigned int u){ return __builtin_bit_cast(half2_t, u); }
__device__ __forceinline__ half2_t pack2(float a, float b){
  half2_t r; r.x = (_Float16)a; r.y = (_Float16)b; return r;   // RTNE
}

// quad_perm DPP cross-lane (VALU pipe, not LDS). ctrl = [l0|l1<<2|l2<<4|l3<<6]
template<int CTRL>
__device__ __forceinline__ float qperm(float x){
  return __int_as_float(__builtin_amdgcn_update_dpp(0, __float_as_int(x), CTRL, 0xF, 0xF, true));
}

// ---------------- kernel 1: 3x3 second-moment stats of x over B*T ----------------
__global__ __launch_bounds__(256) void stats_kernel(const float* __restrict__ x,
                                                    float* __restrict__ stats){
  int t = blockIdx.x * 256 + threadIdx.x;
  const float4* xv = (const float4*)x + (size_t)t * 3;
  float4 a = xv[0], b = xv[1], c = xv[2];
  float x0[4] = {a.x, a.w, b.z, c.y};
  float x1[4] = {a.y, b.x, b.w, c.z};
  float x2[4] = {a.z, b.y, c.x, c.w};
  float s[9] = {0,0,0,0,0,0,0,0,0};
  #pragma unroll
  for (int r=0;r<4;++r){
    s[0]+=x0[r]; s[1]+=x1[r]; s[2]+=x2[r];
    s[3]+=x0[r]*x0[r]; s[4]+=x0[r]*x1[r]; s[5]+=x0[r]*x2[r];
    s[6]+=x1[r]*x1[r]; s[7]+=x1[r]*x2[r]; s[8]+=x2[r]*x2[r];
  }
  __shared__ float red[9][256];
  #pragma unroll
  for (int j=0;j<9;++j) red[j][threadIdx.x] = s[j];
  __syncthreads();
  if (threadIdx.x < 9){
    float sum = 0.f;
    for (int i=0;i<256;++i) sum += red[threadIdx.x][i];
    atomicAdd(&stats[threadIdx.x], sum);
  }
}

// Fold conv + BN(train stats) + gamma/beta into per-channel affine. conv_b cancels.
__device__ __forceinline__ void chan_affine(int c, const float* __restrict__ conv_w,
    const float* __restrict__ bn_g, const float* __restrict__ bn_b,
    const float* __restrict__ stats,
    float& A0, float& A1, float& A2, float& Bc){
  const float Ninv = 1.0f / (float)(B_*T_);
  float m0=stats[0]*Ninv, m1=stats[1]*Ninv, m2=stats[2]*Ninv;
  float c00=stats[3]*Ninv-m0*m0, c01=stats[4]*Ninv-m0*m1, c02=stats[5]*Ninv-m0*m2;
  float c11=stats[6]*Ninv-m1*m1, c12=stats[7]*Ninv-m1*m2, c22=stats[8]*Ninv-m2*m2;
  float w0=conv_w[c*3+0], w1=conv_w[c*3+1], w2=conv_w[c*3+2];
  float var = w0*(w0*c00 + 2.f*(w1*c01 + w2*c02)) + w1*(w1*c11 + 2.f*w2*c12) + w2*w2*c22;
  float sc = bn_g[c] * rsqrtf(var + 1e-5f);
  A0 = w0*sc; A1 = w1*sc; A2 = w2*sc;
  Bc = bn_b[c] - (w0*m0 + w1*m1 + w2*m2)*sc;
}

// ---------------- kernel 2: persistent per-batch LSTM ----------------
// 64 blocks x 512 threads. thread t: k=t>>2 (h index), q=t&3 (32-wide h window / 16-wide
// y window). f16 dot2 datapath; x_t is block-uniform -> scalar(SMEM) loads, 3-step
// prefetch; y-production distributed (yc=t>>3); quad-parallel activations: lane q
// applies A+B*rcp(1+exp2(S*x)) to gate q, quad-perms recombine I*G+F*c and O*tanh(c).
__global__ __launch_bounds__(512,2) void lstm_kernel(
    const float* __restrict__ x,
    const float* __restrict__ conv_w, const float* __restrict__ bn_g,
    const float* __restrict__ bn_b, const float* __restrict__ stats,
    const float* __restrict__ w_ih, const float* __restrict__ b_ih,
    const float* __restrict__ b_hh, const float* __restrict__ w_hh,
    const float* __restrict__ h0, const float* __restrict__ c0,
    const float* __restrict__ out_w, const float* __restrict__ out_b,
    float* __restrict__ out){
  int b = blockIdx.x, t = threadIdx.x;
  int k = t >> 2, q = t & 3;
  int yc = t >> 3;                                  // y channel this thread produces
  __shared__ __align__(16) _Float16 hbuf[2][H_];    // 256 B/buffer, quad-broadcast reads
  __shared__ __align__(16) _Float16 ybuf[2][C1_];

  // recurrent weights as half2: rows {k,128+k,256+k,384+k}, cols [q*32, q*32+32)
  half2_t wh[4][16];
  #pragma unroll
  for (int g=0; g<4; ++g){
    const float4* p = (const float4*)(w_hh + (size_t)(g*H_ + k)*H_ + q*32);
    #pragma unroll
    for (int i=0;i<8;++i){
      float4 v = p[i];
      wh[g][2*i]   = pack2(v.x, v.y);
      wh[g][2*i+1] = pack2(v.z, v.w);
    }
  }
  half2_t wy[4][8];
  #pragma unroll
  for (int g=0; g<4; ++g){
    const float4* p = (const float4*)(w_ih + (size_t)(g*H_ + k)*C1_ + q*16);
    #pragma unroll
    for (int i=0;i<4;++i){
      float4 v = p[i];
      wy[g][2*i]   = pack2(v.x, v.y);
      wy[g][2*i+1] = pack2(v.z, v.w);
    }
  }
  // gate-q bias for this k (lane-parallel activation scheme)
  float biasSel = b_ih[q*H_ + k] + b_hh[q*H_ + k];
  // unified activation constants: sigmoid: S=-log2e, A=0, B=1 ; tanh(G, q==2): S=2log2e, A=1, B=-2
  float S  = (q==2) ?  2.8853900817779268f : -1.4426950408889634f;
  float Aa = (q==2) ?  1.f : 0.f;
  float Bb = (q==2) ? -2.f : 1.f;
  bool bq0 = (q & 1) != 0;

  // per-thread y affine coeffs (channel yc)
  float ya0, ya1, ya2, ya3;
  chan_affine(yc, conv_w, bn_g, bn_b, stats, ya0, ya1, ya2, ya3);

  // scalar (block-uniform) x pipeline: xs = x[step+1], xn = x[step+2]
  const float* xb = x + (size_t)b*T_*3;
  float y0v = fmaf(ya0, xb[0], fmaf(ya1, xb[1], fmaf(ya2, xb[2], ya3)));
  if ((t&7)==0) ybuf[0][yc] = (_Float16)fmaxf(y0v, 0.f);
  float xs0 = xb[3], xs1 = xb[4], xs2 = xb[5];
  float xn0 = xb[6], xn1 = xb[7], xn2 = xb[8];

  float c = c0[(size_t)b*H_ + k];                   // replicated across quad
  if (q == 0) hbuf[0][k] = (_Float16)h0[(size_t)b*H_ + k];
  __syncthreads();

  #pragma unroll 2
  for (int step=0; step<T_; ++step){
    int p = step & 1;                               // const-folded per unrolled copy
    // LDS reads first (latency overlapped by y-production + scalar loads)
    const _Float16* hb = &hbuf[p][q*32];
    uint4 hv0 = *(const uint4*)(hb);
    uint4 hv1 = *(const uint4*)(hb + 8);
    uint4 hv2 = *(const uint4*)(hb + 16);
    uint4 hv3 = *(const uint4*)(hb + 24);
    const _Float16* yb = &ybuf[p][q*16];
    uint4 yv0 = *(const uint4*)(yb);
    uint4 yv1 = *(const uint4*)(yb + 8);
    // produce y[step+1] (writes retire long before barrier)
    float yn = fmaf(ya0, xs0, fmaf(ya1, xs1, fmaf(ya2, xs2, ya3)));
    if ((t&7)==0) ybuf[1-p][yc] = (_Float16)fmaxf(yn, 0.f);
    // advance scalar x pipeline (3-step prefetch depth)
    xs0=xn0; xs1=xn1; xs2=xn2;
    { int t3 = (step+3 < T_) ? step+3 : T_-1;
      const float* xp = xb + 3*t3; xn0=xp[0]; xn1=xp[1]; xn2=xp[2]; }
    // dot-products: 4 gates over 32-wide h window + 16-wide y window
    float acc[4] = {0.f,0.f,0.f,0.f};
    {
      uint4 hv[4] = {hv0, hv1, hv2, hv3};
      #pragma unroll
      for (int i=0;i<4;++i){
        half2_t h0_ = bc2(hv[i].x), h1_ = bc2(hv[i].y), h2_ = bc2(hv[i].z), h3_ = bc2(hv[i].w);
        #pragma unroll
        for (int g=0; g<4; ++g){
          acc[g] = fdot2(wh[g][4*i+0], h0_, acc[g]);
          acc[g] = fdot2(wh[g][4*i+1], h1_, acc[g]);
          acc[g] = fdot2(wh[g][4*i+2], h2_, acc[g]);
          acc[g] = fdot2(wh[g][4*i+3], h3_, acc[g]);
        }
      }
      uint4 yv[2] = {yv0, yv1};
      #pragma unroll
      for (int i=0;i<2;++i){
        half2_t y0_ = bc2(yv[i].x), y1_ = bc2(yv[i].y), y2_ = bc2(yv[i].z), y3_ = bc2(yv[i].w);
        #pragma unroll
        for (int g=0; g<4; ++g){
          acc[g] = fdot2(wy[g][4*i+0], y0_, acc[g]);
          acc[g] = fdot2(wy[g][4*i+1], y1_, acc[g]);
          acc[g] = fdot2(wy[g][4*i+2], y2_, acc[g]);
          acc[g] = fdot2(wy[g][4*i+3], y3_, acc[g]);
        }
      }
    }
    // quad butterfly: all 4 gate sums complete in every lane
    #pragma unroll
    for (int g=0; g<4; ++g){
      acc[g] += qperm<0xB1>(acc[g]);                // quad_perm [1,0,3,2]
      acc[g] += qperm<0x4E>(acc[g]);                // quad_perm [2,3,0,1]
    }
    // lane q activates gate q: I@0, F@1, G@2, O@3
    float s01 = bq0 ? acc[1] : acc[0];
    float s23 = bq0 ? acc[3] : acc[2];
    float v   = ((q & 2) ? s23 : s01) + biasSel;
    float e   = __builtin_amdgcn_exp2f(S * v);
    float act = fmaf(Bb, __builtin_amdgcn_rcpf(1.f + e), Aa);
    // recombine: c' = I*G + F*c ; broadcast; h = O*tanh(c')
    float bpart = qperm<0x4E>(act);                 // lane0<-G, lane1<-O, ...
    float pp    = act * (bq0 ? c : bpart);          // lane0: I*G, lane1: F*c
    float cp    = pp + qperm<0xB1>(pp);             // lane0: I*G + F*c
    cp = qperm<0x00>(cp);                           // broadcast c' to quad
    c = cp;
    float e2 = __builtin_amdgcn_exp2f(2.8853900817779268f * cp);
    float th = fmaf(-2.f, __builtin_amdgcn_rcpf(1.f + e2), 1.f);
    float d  = qperm<0x1B>(act);                    // lane0 <- O (lane3)
    float h  = th * d;
    if (q == 0) hbuf[1-p][k] = (_Float16)h;
    __syncthreads();
  }
  // classifier epilogue on final h (T even -> buffer 0)
  if (t < NCLS_){
    float s = out_b[t];
    #pragma unroll 8
    for (int kk=0; kk<H_; ++kk)
      s = fmaf(out_w[t*H_ + kk], (float)hbuf[0][kk], s);
    out[(size_t)b*NCLS_ + t] = s;
  }
}

extern "C" void kernel_launch(void* const* d_in, const int* in_sizes, int n_in,
                              void* d_out, int out_size, void* d_ws, size_t ws_size,
                              hipStream_t stream){
  const float* x      = (const float*)d_in[0];
  const float* conv_w = (const float*)d_in[1];
  // d_in[2] = conv_b: cancels exactly inside BN(train stats) — unused
  const float* bn_g   = (const float*)d_in[3];
  const float* bn_b   = (const float*)d_in[4];
  const float* w_ih   = (const float*)d_in[5];
  const float* b_ih   = (const float*)d_in[6];
  const float* w_hh   = (const float*)d_in[7];
  const float* b_hh   = (const float*)d_in[8];
  const float* out_w  = (const float*)d_in[9];
  const float* out_b  = (const float*)d_in[10];
  const float* h0     = (const float*)d_in[11];
  const float* c0     = (const float*)d_in[12];
  float* out   = (float*)d_out;
  float* stats = (float*)d_ws;

  hipMemsetAsync(d_ws, 0, 64, stream);
  stats_kernel<<<256, 256, 0, stream>>>(x, stats);
  lstm_kernel<<<B_, 512, 0, stream>>>(x, conv_w, bn_g, bn_b, stats,
                                      w_ih, b_ih, b_hh, w_hh, h0, c0, out_w, out_b, out);
}